// Round 7
// baseline (162.401 us; speedup 1.0000x reference)
//
#include <hip/hip_runtime.h>

// EquivariantLieConvLayer on MI355X — balanced-bracket edition.
//
//   agg[n] = ab*am * bracket( S[n], feat[n] ),  S[n] = sum_{e: tgt(e)=n} feat[src(e)]
//   out[n] = feat[n] + agg[n] + us*aw * bracket(agg[n], agg[n])
//
// fill: bucket edges by target (64 slots, deg~Poisson(8)); block 0 sorts the
//       600 structure constants by output k, pads to 640, packs each term as
//       i | j<<8 | k<<16 | segflag<<24 (+ float v), stored transposed so lane
//       l's 10 terms sit at phys = d*64 + l (coalesced register load).
// node: terms live in 20 registers/lane; per bracket each lane runs EXACTLY 10
//       fully-unrolled term-iterations, flushing run sums at k-boundaries with
//       LDS float atomics. Wave-private LDS slices, zero block barriers in the
//       node loop, 1-node-deep gather pipeline.

#define ALG    248
#define ALG4    62     // ALG/4
#define SLOTS   64
#define WPB      4
#define NBLK  2048
#define TPL     10     // terms per lane
#define NPAD   640     // TPL * 64

// ---- fill: bucket edges; block 0 packs/sorts/transposes terms -------------
__global__ __launch_bounds__(256) void elc_fill(
    const int* __restrict__ ei, int E,
    int* __restrict__ cnt, int* __restrict__ slot,
    const int* __restrict__ ci, const int* __restrict__ cj,
    const int* __restrict__ ck, const float* __restrict__ cv,
    int* __restrict__ g_tij, float* __restrict__ g_tv, int nnz)
{
    const int tid = threadIdx.x;

    if (blockIdx.x == 0) {
        __shared__ int   s_cnt[256];
        __shared__ int   s_scan[256];
        __shared__ int   s_cur[256];
        __shared__ int   ls_k[NPAD];
        __shared__ int   ls_ij[NPAD];
        __shared__ float ls_v[NPAD];

        s_cnt[tid] = 0;
        for (int t = tid; t < NPAD; t += 256) { ls_k[t] = 0; ls_ij[t] = 0; ls_v[t] = 0.f; }
        __syncthreads();
        for (int t = tid; t < nnz; t += 256) atomicAdd(&s_cnt[ck[t]], 1);
        __syncthreads();
        int v = s_cnt[tid];
        s_scan[tid] = v;
        __syncthreads();
        for (int off = 1; off < 256; off <<= 1) {
            int u = (tid >= off) ? s_scan[tid - off] : 0;
            __syncthreads();
            s_scan[tid] += u;
            __syncthreads();
        }
        s_cur[tid] = s_scan[tid] - v;
        __syncthreads();
        for (int t = tid; t < nnz; t += 256) {
            const int k = ck[t];
            const int p = atomicAdd(&s_cur[k], 1);
            ls_k[p]  = k;
            ls_ij[p] = ci[t] | (cj[t] << 8);
            ls_v[p]  = cv[t];
        }
        __syncthreads();
        for (int p = tid; p < NPAD; p += 256) {
            const int k  = ls_k[p];
            const int fl = (p + 1 < NPAD && ls_k[p + 1] == k) ? 0 : 1;
            const int w  = ls_ij[p] | (k << 16) | (fl << 24);
            const int phys = (p % TPL) * 64 + (p / TPL);   // transpose
            g_tij[phys] = w;
            g_tv[phys]  = ls_v[p];
        }
    }

    for (int e = blockIdx.x * 256 + tid; e < E; e += gridDim.x * 256) {
        const int t = ei[E + e];                    // target
        const int p = atomicAdd(&cnt[t], 1);
        if (p < SLOTS) slot[t * SLOTS + p] = ei[e]; // source
    }
}

// ---- node: register terms, balanced brackets, pipelined -------------------
__global__ __launch_bounds__(256) void elc_node(
    const float* __restrict__ feat,
    const int*   __restrict__ cnt,
    const int*   __restrict__ slot,
    const int*   __restrict__ g_tij,
    const float* __restrict__ g_tv,
    const float* __restrict__ p_am, const float* __restrict__ p_ab,
    const float* __restrict__ p_aw, const float* __restrict__ p_us,
    float* __restrict__ out, int N)
{
    __shared__ __align__(16) float s_tg[WPB][ALG];
    __shared__ __align__(16) float s_S[WPB][ALG];   // reused as 'up' staging
    __shared__ float s_ag[WPB][ALG];

    const int tid  = threadIdx.x;
    const int lane = tid & 63;
    const int wave = tid >> 6;
    const float4* feat4 = (const float4*)feat;

    // lane-private terms, loop-invariant: 10 packed words + 10 values
    int   tw[TPL];
    float tv[TPL];
#pragma unroll
    for (int d = 0; d < TPL; ++d) {
        tw[d] = g_tij[d * 64 + lane];   // coalesced
        tv[d] = g_tv[d * 64 + lane];
    }

    const float cab   = (*p_ab) * (*p_am);
    const float scale = (*p_us) * (*p_aw);

    float* tg = s_tg[wave];
    float* S  = s_S[wave];
    float* ag = s_ag[wave];

    const int stride = NBLK * WPB;
    int n = blockIdx.x * WPB + wave;

    // prologue loads
    int deg_c = 0, sn_c = 0;
    float4 tgt_c = make_float4(0.f, 0.f, 0.f, 0.f);
    if (n < N) {
        deg_c = min(cnt[n], SLOTS);
        sn_c  = slot[n * SLOTS + lane];
        if (lane < ALG4) tgt_c = feat4[(size_t)n * ALG4 + lane];
    }

    int    nP   = -1;
    float4 accP = make_float4(0.f, 0.f, 0.f, 0.f);
    float4 tgtP = make_float4(0.f, 0.f, 0.f, 0.f);

    while (true) {
        const bool have_cur = (n < N);
        const int  n_next   = n + stride;

        // 1. issue gathers for current node (8 deep)
        float4 f[8];
        if (have_cur) {
#pragma unroll
            for (int d = 0; d < 8; ++d) {
                f[d] = make_float4(0.f, 0.f, 0.f, 0.f);
                const int sd = __shfl(sn_c, d);
                if (d < deg_c && lane < ALG4)
                    f[d] = feat4[(size_t)sd * ALG4 + lane];
            }
        }

        // 2. prefetch next node metadata
        int deg_n = 0, sn_n = 0;
        float4 tgt_n = make_float4(0.f, 0.f, 0.f, 0.f);
        if (have_cur && n_next < N) {
            deg_n = min(cnt[n_next], SLOTS);
            sn_n  = slot[n_next * SLOTS + lane];
            if (lane < ALG4) tgt_n = feat4[(size_t)n_next * ALG4 + lane];
        }

        // 3. brackets + store for PREVIOUS node (LDS/VALU only)
        if (nP >= 0) {
            if (lane < ALG4) {
                ((float4*)tg)[lane] = tgtP;
                ((float4*)S)[lane]  = accP;
            }
#pragma unroll
            for (int q = 0; q < 4; ++q) {
                const int k = lane + 64 * q;
                if (k < ALG) ag[k] = 0.f;
            }
            // bracket 1: ag = cab * C(S, tg)   (balanced: 10 iters/lane)
            float acc = 0.f;
#pragma unroll
            for (int d = 0; d < TPL; ++d) {
                const int w = tw[d];
                const int i = w & 255;
                const int j = (w >> 8) & 255;
                acc = fmaf(tv[d] * S[i], tg[j], acc);
                if ((w & (1 << 24)) || d == TPL - 1) {
                    atomicAdd(&ag[(w >> 16) & 255], cab * acc);
                    acc = 0.f;
                }
            }
            // up := tg + ag  (reuse S)
#pragma unroll
            for (int q = 0; q < 4; ++q) {
                const int k = lane + 64 * q;
                if (k < ALG) S[k] = tg[k] + ag[k];
            }
            // bracket 2: up += scale * C(ag, ag)
            float acc2 = 0.f;
#pragma unroll
            for (int d = 0; d < TPL; ++d) {
                const int w = tw[d];
                const int i = w & 255;
                const int j = (w >> 8) & 255;
                acc2 = fmaf(tv[d] * ag[i], ag[j], acc2);
                if ((w & (1 << 24)) || d == TPL - 1) {
                    atomicAdd(&S[(w >> 16) & 255], scale * acc2);
                    acc2 = 0.f;
                }
            }
#pragma unroll
            for (int q = 0; q < 4; ++q) {
                const int k = lane + 64 * q;
                if (k < ALG)
                    out[(size_t)nP * ALG + k] = S[k];
            }
        }

        if (!have_cur) break;

        // 4. consume gathers
        float4 acc = make_float4(0.f, 0.f, 0.f, 0.f);
#pragma unroll
        for (int d = 0; d < 8; ++d) {
            acc.x += f[d].x; acc.y += f[d].y;
            acc.z += f[d].z; acc.w += f[d].w;
        }
        for (int d = 8; d < deg_c; ++d) {      // rare tail (P(deg>8)~0.4)
            const int sd = __shfl(sn_c, d);
            if (lane < ALG4) {
                const float4 fd = feat4[(size_t)sd * ALG4 + lane];
                acc.x += fd.x; acc.y += fd.y; acc.z += fd.z; acc.w += fd.w;
            }
        }

        // 5. rotate pipeline
        nP = n; accP = acc; tgtP = tgt_c;
        n = n_next; deg_c = deg_n; sn_c = sn_n; tgt_c = tgt_n;
    }
}

extern "C" void kernel_launch(void* const* d_in, const int* in_sizes, int n_in,
                              void* d_out, int out_size, void* d_ws, size_t ws_size,
                              hipStream_t stream) {
    const float* feat = (const float*)d_in[0];
    const int*   ei   = (const int*)d_in[1];
    const int*   ci   = (const int*)d_in[2];
    const int*   cj   = (const int*)d_in[3];
    const int*   ck   = (const int*)d_in[4];
    const float* cv   = (const float*)d_in[5];
    const float* p_am = (const float*)d_in[6];
    const float* p_ab = (const float*)d_in[7];
    const float* p_aw = (const float*)d_in[8];
    const float* p_us = (const float*)d_in[9];
    float* out = (float*)d_out;

    const int N   = in_sizes[0] / ALG;   // 20000
    const int E   = in_sizes[1] / 2;     // 160000
    const int nnz = in_sizes[5];         // 600  (<= NPAD)

    // ---- workspace layout (~5.2 MB) ----
    char* w = (char*)d_ws;
    int*   g_tij = (int*)w;               w += (size_t)NPAD * sizeof(int);
    float* g_tv  = (float*)w;             w += (size_t)NPAD * sizeof(float);
    int*   cnt   = (int*)w;               w += (size_t)N * sizeof(int);
    int*   slot  = (int*)w;

    hipMemsetAsync(cnt, 0, (size_t)N * sizeof(int), stream);

    elc_fill<<<1024, 256, 0, stream>>>(ei, E, cnt, slot,
                                       ci, cj, ck, cv, g_tij, g_tv, nnz);
    elc_node<<<NBLK, 256, 0, stream>>>(feat, cnt, slot, g_tij, g_tv,
                                       p_am, p_ab, p_aw, p_us, out, N);
}